// Round 17
// baseline (363.350 us; speedup 1.0000x reference)
//
#include <hip/hip_runtime.h>
#include <math.h>

#define MID 512
#define NB  65536
#define G   4096
#define NBLK 258
#define PTS  4128   // 258 blocks * 16 points; table point p holds x = (p-1)/G

struct NetP { const float *w1,*b1,*w2,*b2,*w3,*b3; };
struct AllP { NetP n[3]; float* table; };

// ---------------------------------------------------------------------------
// Kernel 0: transpose W2 (512x512) -> W2T[k][n] per net.
// ---------------------------------------------------------------------------
__global__ __launch_bounds__(256)
void k_prep(AllP P, float* __restrict__ w2t)
{
    __shared__ float t[32][33];
    const int net = blockIdx.z;
    const float* src = (net == 0) ? P.n[0].w2 : (net == 1) ? P.n[1].w2 : P.n[2].w2;
    float* dst = w2t + (size_t)net * MID * MID;
    const int bx = blockIdx.x * 32, by = blockIdx.y * 32;
    const int tx = threadIdx.x & 31, ty = threadIdx.x >> 5;   // ty 0..7
    #pragma unroll
    for (int j = 0; j < 4; ++j)
        t[ty + 8 * j][tx] = src[(size_t)(by + ty + 8 * j) * MID + bx + tx];
    __syncthreads();
    #pragma unroll
    for (int j = 0; j < 4; ++j)
        dst[(size_t)(bx + ty + 8 * j) * MID + by + tx] = t[tx][ty + 8 * j];
}

// ---------------------------------------------------------------------------
// Kernel 1: fused SIREN, 128 threads (2 waves) x 16 points/block, 774 blocks
// (3.02/CU balanced). P=16 POINTS x C=4 COLS per thread: W-bytes/FMA = 4/16
// = 0.25 -> 32 B/cyc/CU at full VALU, HALF of R16's 64 B/cyc which sat
// exactly AT the per-CU L1/L2 bandwidth ceiling (the real R9-R16 limiter:
// VALUBusy pinned ~47% at the BW equilibrium, insensitive to LDS tweaks).
// Wave w = col-half ch (no duplicate W reads). Each wave-k: 1 global b128
// (1KB, L2-hit) + 4 wave-uniform LDS broadcasts feed 64 FMA instrs.
// 16 acc f4 + unroll-4 window ~ 150-220 VGPR: 128-thr blocks +
// waves_per_eu(1,2) give the 512-reg budget (R11 precedent: VGPR 164, no
// spill); 512-thr blocks hard-cap at 128 (R13/R14) so this shape NEEDS 2-wave
// blocks. Occupancy is grid-limited (6 waves/CU) but each wave-k has 64
// independent FMAs per load. Layer 3: single pass, XOR swizzle.
// ---------------------------------------------------------------------------
__global__ __attribute__((amdgpu_waves_per_eu(1, 2))) __launch_bounds__(128)
void k_siren(AllP P, const float* __restrict__ w2t)
{
    __shared__ float sbuf[MID * 16];    // 32 KB: h1 [k][m] during loop; h2 after

    const int tid = threadIdx.x;        // 0..127
    const int net = blockIdx.y;
    const int m0  = blockIdx.x * 16;
    NetP np;
    if (net == 0)      np = P.n[0];
    else if (net == 1) np = P.n[1];
    else               np = P.n[2];
    const float* wslab = w2t + (size_t)net * MID * MID;

    const int c  = tid & 63;
    const int ch = tid >> 6;    // wave 0/1 -> cols ch*256 + c*4 .. +3

    // ---- fill h1[k][m] = sin(sin(4*(x_m*w1[k]+b1[k]))), 64 entries/thread
    {
        const float invG = 1.0f / (float)G;
        for (int j = 0; j < 64; ++j) {
            const int idx = tid + j * 128;        // = k*16 + m
            const int k = idx >> 4, m = idx & 15;
            const float xv = ((float)(m0 + m) - 1.0f) * invG;
            const float z = 4.f * fmaf(xv, np.w1[k], np.b1[k]);
            sbuf[idx] = sinf(sinf(z));
        }
    }
    __syncthreads();

#define ACC_DECL(i) float4 a##i = make_float4(0.f,0.f,0.f,0.f);
    ACC_DECL(0)  ACC_DECL(1)  ACC_DECL(2)  ACC_DECL(3)
    ACC_DECL(4)  ACC_DECL(5)  ACC_DECL(6)  ACC_DECL(7)
    ACC_DECL(8)  ACC_DECL(9)  ACC_DECL(10) ACC_DECL(11)
    ACC_DECL(12) ACC_DECL(13) ACC_DECL(14) ACC_DECL(15)

#define FMA4(i, hv) \
        a##i.x = fmaf(hv, wa.x, a##i.x); a##i.y = fmaf(hv, wa.y, a##i.y); \
        a##i.z = fmaf(hv, wa.z, a##i.z); a##i.w = fmaf(hv, wa.w, a##i.w);

    // ---- K loop: barrier-free. 1 global b128 (W, L2-hit) + 4 broadcast LDS
    //      b128 (h for all 16 points) feed 64 FMAs per thread per k.
    {
        const float* wp = wslab + ch * 256 + c * 4;
        #pragma unroll 4
        for (int k = 0; k < MID; ++k) {
            const float4 wa = *reinterpret_cast<const float4*>(wp + (size_t)k * MID);
            const float4 hA = *reinterpret_cast<const float4*>(&sbuf[k * 16 + 0]);
            const float4 hB = *reinterpret_cast<const float4*>(&sbuf[k * 16 + 4]);
            const float4 hC = *reinterpret_cast<const float4*>(&sbuf[k * 16 + 8]);
            const float4 hD = *reinterpret_cast<const float4*>(&sbuf[k * 16 + 12]);
            FMA4(0,  hA.x) FMA4(1,  hA.y) FMA4(2,  hA.z) FMA4(3,  hA.w)
            FMA4(4,  hB.x) FMA4(5,  hB.y) FMA4(6,  hB.z) FMA4(7,  hB.w)
            FMA4(8,  hC.x) FMA4(9,  hC.y) FMA4(10, hC.z) FMA4(11, hC.w)
            FMA4(12, hD.x) FMA4(13, hD.y) FMA4(14, hD.z) FMA4(15, hD.w)
        }
    }
    __syncthreads();   // h1 no longer needed; sbuf becomes the h2 buffer

    {   // epilogue: h2 = sin(sin(4*(z + b2))) — this thread's 4 cols, 16 pts
        const float4 bv = *reinterpret_cast<const float4*>(np.b2 + ch * 256 + c * 4);
#define SS1(v, b) v = sinf(sinf(4.f * ((v) + (b))));
#define SSROW(i) SS1(a##i.x, bv.x) SS1(a##i.y, bv.y) SS1(a##i.z, bv.z) SS1(a##i.w, bv.w)
        SSROW(0)  SSROW(1)  SSROW(2)  SSROW(3)
        SSROW(4)  SSROW(5)  SSROW(6)  SSROW(7)
        SSROW(8)  SSROW(9)  SSROW(10) SSROW(11)
        SSROW(12) SSROW(13) SSROW(14) SSROW(15)
    }

    // layer 3: h2 (16 pts x 512 = 32KB) in sbuf, XOR swizzle:
    // phys f4 (row, n4) = row*512floats.. row*128 + ((n4 ^ row) & 127),
    // n4 = ch*64 + c. Store: row uniform/instr, n4 lane-permutation -> 0-conflict.
    {
        const int n4 = ch * 64 + c;
#define L3ST(i) \
        *reinterpret_cast<float4*>(&sbuf[(i) * 512 + ((n4 ^ (i)) & 127) * 4]) = a##i;
        L3ST(0)  L3ST(1)  L3ST(2)  L3ST(3)
        L3ST(4)  L3ST(5)  L3ST(6)  L3ST(7)
        L3ST(8)  L3ST(9)  L3ST(10) L3ST(11)
        L3ST(12) L3ST(13) L3ST(14) L3ST(15)
    }
    __syncthreads();

    {   // m = tid&15 (point), jg = tid>>4 (0..7) -> output cols jg*4 .. +3
        const int m  = tid & 15;
        const int jg = tid >> 4;
        const float* wr0 = np.w3 + (size_t)(jg * 4 + 0) * MID;
        const float* wr1 = np.w3 + (size_t)(jg * 4 + 1) * MID;
        const float* wr2 = np.w3 + (size_t)(jg * 4 + 2) * MID;
        const float* wr3 = np.w3 + (size_t)(jg * 4 + 3) * MID;
        float q0 = 0.f, q1 = 0.f, q2 = 0.f, q3 = 0.f;
        #pragma unroll 4
        for (int qq = 0; qq < 128; ++qq) {
            const float4 h  = *reinterpret_cast<const float4*>(
                &sbuf[m * 512 + ((qq ^ m) & 127) * 4]);
            const float4 w0 = *reinterpret_cast<const float4*>(wr0 + qq * 4);
            const float4 w1 = *reinterpret_cast<const float4*>(wr1 + qq * 4);
            const float4 w2 = *reinterpret_cast<const float4*>(wr2 + qq * 4);
            const float4 w3 = *reinterpret_cast<const float4*>(wr3 + qq * 4);
            q0 = fmaf(h.w, w0.w, fmaf(h.z, w0.z, fmaf(h.y, w0.y, fmaf(h.x, w0.x, q0))));
            q1 = fmaf(h.w, w1.w, fmaf(h.z, w1.z, fmaf(h.y, w1.y, fmaf(h.x, w1.x, q1))));
            q2 = fmaf(h.w, w2.w, fmaf(h.z, w2.z, fmaf(h.y, w2.y, fmaf(h.x, w2.x, q2))));
            q3 = fmaf(h.w, w3.w, fmaf(h.z, w3.z, fmaf(h.y, w3.y, fmaf(h.x, w3.x, q3))));
        }
        const float4 b3v = *reinterpret_cast<const float4*>(np.b3 + jg * 4);
        float4 r; r.x = q0 + b3v.x; r.y = q1 + b3v.y; r.z = q2 + b3v.z; r.w = q3 + b3v.w;
        *reinterpret_cast<float4*>(
            &P.table[((size_t)net * PTS + (m0 + m)) * 32 + jg * 4]) = r;
    }
}

// ---------------------------------------------------------------------------
// Kernel 2: Catmull-Rom interp + Tucker contraction — ROUND-6 VERSION VERBATIM
// (measured ~93us. R12 s_load variant ~145us; R7/R10 2-sample spilled.
// Do not touch.)
// ---------------------------------------------------------------------------
#define F4MA(acc, s, rp, k) { const float4 _v = (rp)[k]; \
    acc.x = fmaf((s), _v.x, acc.x); acc.y = fmaf((s), _v.y, acc.y); \
    acc.z = fmaf((s), _v.z, acc.z); acc.w = fmaf((s), _v.w, acc.w); }

#define GROW8(Pfx, w, rp, off) \
    F4MA(Pfx##0,(w),rp,(off)+0) F4MA(Pfx##1,(w),rp,(off)+1) \
    F4MA(Pfx##2,(w),rp,(off)+2) F4MA(Pfx##3,(w),rp,(off)+3) \
    F4MA(Pfx##4,(w),rp,(off)+4) F4MA(Pfx##5,(w),rp,(off)+5) \
    F4MA(Pfx##6,(w),rp,(off)+6) F4MA(Pfx##7,(w),rp,(off)+7)

// Catmull-Rom setup: x*G is EXACT in fp32 (power-of-two scale).
#define CRSETUP(x_, iv, c0, c1, c2, c3) \
    int iv; float c0, c1, c2, c3; { \
        float xx = (x_) * (float)G; \
        int i = (int)xx; i = i < 0 ? 0 : (i > G - 1 ? G - 1 : i); iv = i; \
        float t = xx - (float)i; \
        float t2 = t * t, t3 = t2 * t; \
        c0 = fmaf(-0.5f, t3, t2) - 0.5f * t; \
        c1 = fmaf(1.5f, t3, fmaf(-2.5f, t2, 1.f)); \
        c2 = fmaf(-1.5f, t3, fmaf(2.f, t2, 0.5f * t)); \
        c3 = 0.5f * (t3 - t2); }

__global__ __attribute__((amdgpu_waves_per_eu(2, 4))) __launch_bounds__(256)
void k_ic(const float* __restrict__ table, const float* __restrict__ core,
          const float* __restrict__ x, float* __restrict__ out)
{
    __shared__ float cs[8 * 1024];   // 32 KB: 8 r-rows of C per round
    __shared__ float red[256];

    const int tid = threadIdx.x;
    const int ls  = tid & 63;        // local sample
    const int rh  = tid >> 6;        // 0..3, wave-uniform; r = rb*8+rh*2+{0,1}
    const int g   = blockIdx.x * 64 + ls;

    const float xu = x[(size_t)g * 3 + 0];
    const float xv = x[(size_t)g * 3 + 1];
    const float xw = x[(size_t)g * 3 + 2];

#define DECLZ(Pn) float4 Pn = make_float4(0.f,0.f,0.f,0.f);
    DECLZ(W0) DECLZ(W1) DECLZ(W2) DECLZ(W3) DECLZ(W4) DECLZ(W5) DECLZ(W6) DECLZ(W7)
    DECLZ(V0) DECLZ(V1) DECLZ(V2) DECLZ(V3) DECLZ(V4) DECLZ(V5) DECLZ(V6) DECLZ(V7)
    float2 U0, U1, U2, U3;

    {   // W net (index 2)
        CRSETUP(xw, iw, c0, c1, c2, c3)
        const float4* rp = reinterpret_cast<const float4*>(
            table + ((size_t)2 * PTS + iw) * 32);
        GROW8(W, c0, rp, 0) GROW8(W, c1, rp, 8) GROW8(W, c2, rp, 16) GROW8(W, c3, rp, 24)
    }
    {   // V net (index 1)
        CRSETUP(xv, iv2, c0, c1, c2, c3)
        const float4* rp = reinterpret_cast<const float4*>(
            table + ((size_t)1 * PTS + iv2) * 32);
        GROW8(V, c0, rp, 0) GROW8(V, c1, rp, 8) GROW8(V, c2, rp, 16) GROW8(V, c3, rp, 24)
    }
    {   // U net (index 0): this thread's 8 r-cols = rb*8 + rh*2 + {0,1}
        CRSETUP(xu, iu, c0, c1, c2, c3)
        const float2* up = reinterpret_cast<const float2*>(table + (size_t)iu * 32);
#define UROW(rbv, dst) { \
        const float2 t0 = up[0 * 16 + (rbv) * 4 + rh]; \
        const float2 t1 = up[1 * 16 + (rbv) * 4 + rh]; \
        const float2 t2 = up[2 * 16 + (rbv) * 4 + rh]; \
        const float2 t3 = up[3 * 16 + (rbv) * 4 + rh]; \
        dst.x = fmaf(c0,t0.x,fmaf(c1,t1.x,fmaf(c2,t2.x,c3*t3.x))); \
        dst.y = fmaf(c0,t0.y,fmaf(c1,t1.y,fmaf(c2,t2.y,c3*t3.y))); }
        UROW(0, U0) UROW(1, U1) UROW(2, U2) UROW(3, U3)
    }

#define TQC(rl, s, tq, Wv) { \
    const float4 c4 = *reinterpret_cast<const float4*>( \
        &cs[(rh * 2 + (rl)) * 1024 + (s) * 32 + (tq) * 4]); \
    aa = fmaf(Wv.w, c4.w, fmaf(Wv.z, c4.z, fmaf(Wv.y, c4.y, fmaf(Wv.x, c4.x, aa)))); }

#define SONE(rl, s, vcomp) { float aa = 0.f; \
    TQC(rl, s, 0, W0) TQC(rl, s, 1, W1) TQC(rl, s, 2, W2) TQC(rl, s, 3, W3) \
    TQC(rl, s, 4, W4) TQC(rl, s, 5, W5) TQC(rl, s, 6, W6) TQC(rl, s, 7, W7) \
    tracc = fmaf(vcomp, aa, tracc); }

#define SG(rl, sb, Vv) \
    SONE(rl, 4*(sb)+0, Vv.x) SONE(rl, 4*(sb)+1, Vv.y) \
    SONE(rl, 4*(sb)+2, Vv.z) SONE(rl, 4*(sb)+3, Vv.w)

#define RL1(rl, ucomp) { float tracc = 0.f; \
    SG(rl, 0, V0) SG(rl, 1, V1) SG(rl, 2, V2) SG(rl, 3, V3) \
    SG(rl, 4, V4) SG(rl, 5, V5) SG(rl, 6, V6) SG(rl, 7, V7) \
    o = fmaf(ucomp, tracc, o); }

#define RBLOCK(rb) { \
    __syncthreads(); \
    _Pragma("unroll") \
    for (int cc = 0; cc < 8; ++cc) \
        *reinterpret_cast<float4*>(&cs[cc * 1024 + tid * 4]) = \
            *reinterpret_cast<const float4*>(core + (size_t)((rb) * 8 + cc) * 1024 + tid * 4); \
    __syncthreads(); \
    RL1(0, U##rb.x) RL1(1, U##rb.y) }

    float o = 0.f;
    RBLOCK(0) RBLOCK(1) RBLOCK(2) RBLOCK(3)

    red[tid] = o;
    __syncthreads();
    if (tid < 64)
        out[blockIdx.x * 64 + tid] =
            red[tid] + red[tid + 64] + red[tid + 128] + red[tid + 192];
}

// ---------------------------------------------------------------------------
extern "C" void kernel_launch(void* const* d_in, const int* in_sizes, int n_in,
                              void* d_out, int out_size, void* d_ws, size_t ws_size,
                              hipStream_t stream)
{
    AllP P;
    for (int net = 0; net < 3; ++net) {
        const int b = 1 + net * 6;
        P.n[net].w1 = (const float*)d_in[b + 0];
        P.n[net].b1 = (const float*)d_in[b + 1];
        P.n[net].w2 = (const float*)d_in[b + 2];
        P.n[net].b2 = (const float*)d_in[b + 3];
        P.n[net].w3 = (const float*)d_in[b + 4];
        P.n[net].b3 = (const float*)d_in[b + 5];
    }
    const float* xin  = (const float*)d_in[0];
    const float* core = (const float*)d_in[19];
    float* wsf   = (float*)d_ws;
    float* table = wsf;                            // 3*4128*32 = 1.58 MB
    float* w2t   = wsf + (size_t)3 * PTS * 32;     // 3*512*512 = 3.00 MB
    P.table = table;

    k_prep <<<dim3(16, 16, 3), 256, 0, stream>>>(P, w2t);
    k_siren<<<dim3(NBLK, 3), 128, 0, stream>>>(P, w2t);
    k_ic   <<<NB / 64, 256, 0, stream>>>(table, core, xin, (float*)d_out);
}

// Round 18
// 277.749 us; speedup vs baseline: 1.3082x; 1.3082x over previous
//
#include <hip/hip_runtime.h>
#include <math.h>

#define MID 512
#define NB  65536
#define G   4096
#define NBLK 258
#define PTS  4128   // 258 blocks * 16 points; table point p holds x = (p-1)/G

struct NetP { const float *w1,*b1,*w2,*b2,*w3,*b3; };
struct AllP { NetP n[3]; float* table; };

// ---------------------------------------------------------------------------
// Kernel 0: transpose W2 (512x512) -> W2T[k][n] per net.
// ---------------------------------------------------------------------------
__global__ __launch_bounds__(256)
void k_prep(AllP P, float* __restrict__ w2t)
{
    __shared__ float t[32][33];
    const int net = blockIdx.z;
    const float* src = (net == 0) ? P.n[0].w2 : (net == 1) ? P.n[1].w2 : P.n[2].w2;
    float* dst = w2t + (size_t)net * MID * MID;
    const int bx = blockIdx.x * 32, by = blockIdx.y * 32;
    const int tx = threadIdx.x & 31, ty = threadIdx.x >> 5;   // ty 0..7
    #pragma unroll
    for (int j = 0; j < 4; ++j)
        t[ty + 8 * j][tx] = src[(size_t)(by + ty + 8 * j) * MID + bx + tx];
    __syncthreads();
    #pragma unroll
    for (int j = 0; j < 4; ++j)
        dst[(size_t)(bx + ty + 8 * j) * MID + by + tx] = t[tx][ty + 8 * j];
}

// ---------------------------------------------------------------------------
// Kernel 1: fused SIREN, 256 threads x 16 points/block, 774 blocks (3.02/CU,
// 12 waves/CU — R17 proved occupancy must NOT drop: its 128-thr P=16 hit 1.5
// waves/SIMD and regressed to 264us on exposed L2 latency).
// Tile: P=16 POINTS x C=2 COLS per thread. Wave w = col QUARTER; lane covers
// cols w*128+c*2, +1. Per k: 1 global b64 (512B/wave, L2-hit) + 4 broadcast
// h reads feed 32 FMAs -> 32 B/cyc/CU vector-memory demand, HALF of R16's
// 64 B/cyc which sat at the per-CU L2-link ceiling (~56 B/cyc; VALUBusy was
// pinned at 47% = the BW equilibrium). Acc = 16 float2 = 32 floats (the
// proven VGPR~100 class, no spill under (2,8): R15/R16 precedent).
// Layer 3: float2 stores with XOR key 2*row == R16's float4 read pattern
// (2qq^2m = 2(qq^m)) -> read loop identical to R16 (measured 0 conflicts).
// ---------------------------------------------------------------------------
__global__ __attribute__((amdgpu_waves_per_eu(2, 8))) __launch_bounds__(256)
void k_siren(AllP P, const float* __restrict__ w2t)
{
    __shared__ float sbuf[MID * 16];    // 32 KB: h1 [k][m] during loop; h2 after

    const int tid = threadIdx.x;
    const int net = blockIdx.y;
    const int m0  = blockIdx.x * 16;
    NetP np;
    if (net == 0)      np = P.n[0];
    else if (net == 1) np = P.n[1];
    else               np = P.n[2];
    const float* wslab = w2t + (size_t)net * MID * MID;

    const int c  = tid & 63;
    const int w  = tid >> 6;          // wave 0..3 -> col quarter
    const int cw = w * 128 + c * 2;   // first of this thread's 2 cols

    // ---- fill h1[k][m] = sin(sin(4*(x_m*w1[k]+b1[k]))), 32 entries/thread
    {
        const float invG = 1.0f / (float)G;
        for (int j = 0; j < 32; ++j) {
            const int idx = tid + j * 256;        // = k*16 + m
            const int k = idx >> 4, m = idx & 15;
            const float xv = ((float)(m0 + m) - 1.0f) * invG;
            const float z = 4.f * fmaf(xv, np.w1[k], np.b1[k]);
            sbuf[idx] = sinf(sinf(z));
        }
    }
    __syncthreads();

#define ACC_DECL(i) float2 a##i = make_float2(0.f, 0.f);
    ACC_DECL(0)  ACC_DECL(1)  ACC_DECL(2)  ACC_DECL(3)
    ACC_DECL(4)  ACC_DECL(5)  ACC_DECL(6)  ACC_DECL(7)
    ACC_DECL(8)  ACC_DECL(9)  ACC_DECL(10) ACC_DECL(11)
    ACC_DECL(12) ACC_DECL(13) ACC_DECL(14) ACC_DECL(15)

#define FMA2(i, hv) \
        a##i.x = fmaf(hv, wa.x, a##i.x); a##i.y = fmaf(hv, wa.y, a##i.y);

    // ---- K loop: barrier-free. 1 global b64 (W, L2-hit) + 4 broadcast LDS
    //      b128 (h for all 16 points) feed 32 FMAs per thread per k.
    {
        const float* wp = wslab + cw;
        #pragma unroll 4
        for (int k = 0; k < MID; ++k) {
            const float2 wa = *reinterpret_cast<const float2*>(wp + (size_t)k * MID);
            const float4 hA = *reinterpret_cast<const float4*>(&sbuf[k * 16 + 0]);
            const float4 hB = *reinterpret_cast<const float4*>(&sbuf[k * 16 + 4]);
            const float4 hC = *reinterpret_cast<const float4*>(&sbuf[k * 16 + 8]);
            const float4 hD = *reinterpret_cast<const float4*>(&sbuf[k * 16 + 12]);
            FMA2(0,  hA.x) FMA2(1,  hA.y) FMA2(2,  hA.z) FMA2(3,  hA.w)
            FMA2(4,  hB.x) FMA2(5,  hB.y) FMA2(6,  hB.z) FMA2(7,  hB.w)
            FMA2(8,  hC.x) FMA2(9,  hC.y) FMA2(10, hC.z) FMA2(11, hC.w)
            FMA2(12, hD.x) FMA2(13, hD.y) FMA2(14, hD.z) FMA2(15, hD.w)
        }
    }
    __syncthreads();   // h1 no longer needed; sbuf becomes the h2 buffer

    {   // epilogue: h2 = sin(sin(4*(z + b2))) — this thread's 2 cols, 16 pts
        const float2 bv = *reinterpret_cast<const float2*>(np.b2 + cw);
#define SS1(v, b) v = sinf(sinf(4.f * ((v) + (b))));
#define SSROW(i) SS1(a##i.x, bv.x) SS1(a##i.y, bv.y)
        SSROW(0)  SSROW(1)  SSROW(2)  SSROW(3)
        SSROW(4)  SSROW(5)  SSROW(6)  SSROW(7)
        SSROW(8)  SSROW(9)  SSROW(10) SSROW(11)
        SSROW(12) SSROW(13) SSROW(14) SSROW(15)
    }

    // layer 3: h2 (16 pts x 512 = 32KB) in sbuf. Store float2 with XOR key
    // 2*row at float2 granularity: phys_f2(row, n2) = n2 ^ (2*row). Since
    // 2qq ^ 2m = 2(qq^m), the float4 READ pattern is exactly R16's proven
    // conflict-free sbuf[m*512 + ((qq^m)&127)*4].
    {
        const int n2 = w * 64 + c;   // logical float2 col index 0..255
#define L3ST(i) \
        *reinterpret_cast<float2*>(&sbuf[(i) * 512 + ((n2 ^ (2 * (i))) & 255) * 2]) = a##i;
        L3ST(0)  L3ST(1)  L3ST(2)  L3ST(3)
        L3ST(4)  L3ST(5)  L3ST(6)  L3ST(7)
        L3ST(8)  L3ST(9)  L3ST(10) L3ST(11)
        L3ST(12) L3ST(13) L3ST(14) L3ST(15)
    }
    __syncthreads();

    {   // m = tid&15 (point), jg = tid>>4 (0..15) -> output cols jg*2, jg*2+1
        const int m  = tid & 15;
        const int jg = tid >> 4;
        const float* wr0 = np.w3 + (size_t)(jg * 2) * MID;
        const float* wr1 = wr0 + MID;
        float p0a = 0.f, p0b = 0.f, p1a = 0.f, p1b = 0.f;
        #pragma unroll 8
        for (int qq = 0; qq < 128; ++qq) {
            const float4 h  = *reinterpret_cast<const float4*>(
                &sbuf[m * 512 + ((qq ^ m) & 127) * 4]);
            const float4 w0 = *reinterpret_cast<const float4*>(wr0 + qq * 4);
            const float4 w1 = *reinterpret_cast<const float4*>(wr1 + qq * 4);
            p0a = fmaf(h.y, w0.y, fmaf(h.x, w0.x, p0a));
            p0b = fmaf(h.w, w0.w, fmaf(h.z, w0.z, p0b));
            p1a = fmaf(h.y, w1.y, fmaf(h.x, w1.x, p1a));
            p1b = fmaf(h.w, w1.w, fmaf(h.z, w1.z, p1b));
        }
        const float2 b3v = *reinterpret_cast<const float2*>(np.b3 + jg * 2);
        float2 r; r.x = p0a + p0b + b3v.x; r.y = p1a + p1b + b3v.y;
        *reinterpret_cast<float2*>(
            &P.table[((size_t)net * PTS + (m0 + m)) * 32 + jg * 2]) = r;
    }
}

// ---------------------------------------------------------------------------
// Kernel 2: Catmull-Rom interp + Tucker contraction — ROUND-6 VERSION VERBATIM
// (measured ~93us. R12 s_load variant ~145us; R7/R10 2-sample spilled.
// Do not touch.)
// ---------------------------------------------------------------------------
#define F4MA(acc, s, rp, k) { const float4 _v = (rp)[k]; \
    acc.x = fmaf((s), _v.x, acc.x); acc.y = fmaf((s), _v.y, acc.y); \
    acc.z = fmaf((s), _v.z, acc.z); acc.w = fmaf((s), _v.w, acc.w); }

#define GROW8(Pfx, w, rp, off) \
    F4MA(Pfx##0,(w),rp,(off)+0) F4MA(Pfx##1,(w),rp,(off)+1) \
    F4MA(Pfx##2,(w),rp,(off)+2) F4MA(Pfx##3,(w),rp,(off)+3) \
    F4MA(Pfx##4,(w),rp,(off)+4) F4MA(Pfx##5,(w),rp,(off)+5) \
    F4MA(Pfx##6,(w),rp,(off)+6) F4MA(Pfx##7,(w),rp,(off)+7)

// Catmull-Rom setup: x*G is EXACT in fp32 (power-of-two scale).
#define CRSETUP(x_, iv, c0, c1, c2, c3) \
    int iv; float c0, c1, c2, c3; { \
        float xx = (x_) * (float)G; \
        int i = (int)xx; i = i < 0 ? 0 : (i > G - 1 ? G - 1 : i); iv = i; \
        float t = xx - (float)i; \
        float t2 = t * t, t3 = t2 * t; \
        c0 = fmaf(-0.5f, t3, t2) - 0.5f * t; \
        c1 = fmaf(1.5f, t3, fmaf(-2.5f, t2, 1.f)); \
        c2 = fmaf(-1.5f, t3, fmaf(2.f, t2, 0.5f * t)); \
        c3 = 0.5f * (t3 - t2); }

__global__ __attribute__((amdgpu_waves_per_eu(2, 4))) __launch_bounds__(256)
void k_ic(const float* __restrict__ table, const float* __restrict__ core,
          const float* __restrict__ x, float* __restrict__ out)
{
    __shared__ float cs[8 * 1024];   // 32 KB: 8 r-rows of C per round
    __shared__ float red[256];

    const int tid = threadIdx.x;
    const int ls  = tid & 63;        // local sample
    const int rh  = tid >> 6;        // 0..3, wave-uniform; r = rb*8+rh*2+{0,1}
    const int g   = blockIdx.x * 64 + ls;

    const float xu = x[(size_t)g * 3 + 0];
    const float xv = x[(size_t)g * 3 + 1];
    const float xw = x[(size_t)g * 3 + 2];

#define DECLZ(Pn) float4 Pn = make_float4(0.f,0.f,0.f,0.f);
    DECLZ(W0) DECLZ(W1) DECLZ(W2) DECLZ(W3) DECLZ(W4) DECLZ(W5) DECLZ(W6) DECLZ(W7)
    DECLZ(V0) DECLZ(V1) DECLZ(V2) DECLZ(V3) DECLZ(V4) DECLZ(V5) DECLZ(V6) DECLZ(V7)
    float2 U0, U1, U2, U3;

    {   // W net (index 2)
        CRSETUP(xw, iw, c0, c1, c2, c3)
        const float4* rp = reinterpret_cast<const float4*>(
            table + ((size_t)2 * PTS + iw) * 32);
        GROW8(W, c0, rp, 0) GROW8(W, c1, rp, 8) GROW8(W, c2, rp, 16) GROW8(W, c3, rp, 24)
    }
    {   // V net (index 1)
        CRSETUP(xv, iv2, c0, c1, c2, c3)
        const float4* rp = reinterpret_cast<const float4*>(
            table + ((size_t)1 * PTS + iv2) * 32);
        GROW8(V, c0, rp, 0) GROW8(V, c1, rp, 8) GROW8(V, c2, rp, 16) GROW8(V, c3, rp, 24)
    }
    {   // U net (index 0): this thread's 8 r-cols = rb*8 + rh*2 + {0,1}
        CRSETUP(xu, iu, c0, c1, c2, c3)
        const float2* up = reinterpret_cast<const float2*>(table + (size_t)iu * 32);
#define UROW(rbv, dst) { \
        const float2 t0 = up[0 * 16 + (rbv) * 4 + rh]; \
        const float2 t1 = up[1 * 16 + (rbv) * 4 + rh]; \
        const float2 t2 = up[2 * 16 + (rbv) * 4 + rh]; \
        const float2 t3 = up[3 * 16 + (rbv) * 4 + rh]; \
        dst.x = fmaf(c0,t0.x,fmaf(c1,t1.x,fmaf(c2,t2.x,c3*t3.x))); \
        dst.y = fmaf(c0,t0.y,fmaf(c1,t1.y,fmaf(c2,t2.y,c3*t3.y))); }
        UROW(0, U0) UROW(1, U1) UROW(2, U2) UROW(3, U3)
    }

#define TQC(rl, s, tq, Wv) { \
    const float4 c4 = *reinterpret_cast<const float4*>( \
        &cs[(rh * 2 + (rl)) * 1024 + (s) * 32 + (tq) * 4]); \
    aa = fmaf(Wv.w, c4.w, fmaf(Wv.z, c4.z, fmaf(Wv.y, c4.y, fmaf(Wv.x, c4.x, aa)))); }

#define SONE(rl, s, vcomp) { float aa = 0.f; \
    TQC(rl, s, 0, W0) TQC(rl, s, 1, W1) TQC(rl, s, 2, W2) TQC(rl, s, 3, W3) \
    TQC(rl, s, 4, W4) TQC(rl, s, 5, W5) TQC(rl, s, 6, W6) TQC(rl, s, 7, W7) \
    tracc = fmaf(vcomp, aa, tracc); }

#define SG(rl, sb, Vv) \
    SONE(rl, 4*(sb)+0, Vv.x) SONE(rl, 4*(sb)+1, Vv.y) \
    SONE(rl, 4*(sb)+2, Vv.z) SONE(rl, 4*(sb)+3, Vv.w)

#define RL1(rl, ucomp) { float tracc = 0.f; \
    SG(rl, 0, V0) SG(rl, 1, V1) SG(rl, 2, V2) SG(rl, 3, V3) \
    SG(rl, 4, V4) SG(rl, 5, V5) SG(rl, 6, V6) SG(rl, 7, V7) \
    o = fmaf(ucomp, tracc, o); }

#define RBLOCK(rb) { \
    __syncthreads(); \
    _Pragma("unroll") \
    for (int cc = 0; cc < 8; ++cc) \
        *reinterpret_cast<float4*>(&cs[cc * 1024 + tid * 4]) = \
            *reinterpret_cast<const float4*>(core + (size_t)((rb) * 8 + cc) * 1024 + tid * 4); \
    __syncthreads(); \
    RL1(0, U##rb.x) RL1(1, U##rb.y) }

    float o = 0.f;
    RBLOCK(0) RBLOCK(1) RBLOCK(2) RBLOCK(3)

    red[tid] = o;
    __syncthreads();
    if (tid < 64)
        out[blockIdx.x * 64 + tid] =
            red[tid] + red[tid + 64] + red[tid + 128] + red[tid + 192];
}

// ---------------------------------------------------------------------------
extern "C" void kernel_launch(void* const* d_in, const int* in_sizes, int n_in,
                              void* d_out, int out_size, void* d_ws, size_t ws_size,
                              hipStream_t stream)
{
    AllP P;
    for (int net = 0; net < 3; ++net) {
        const int b = 1 + net * 6;
        P.n[net].w1 = (const float*)d_in[b + 0];
        P.n[net].b1 = (const float*)d_in[b + 1];
        P.n[net].w2 = (const float*)d_in[b + 2];
        P.n[net].b2 = (const float*)d_in[b + 3];
        P.n[net].w3 = (const float*)d_in[b + 4];
        P.n[net].b3 = (const float*)d_in[b + 5];
    }
    const float* xin  = (const float*)d_in[0];
    const float* core = (const float*)d_in[19];
    float* wsf   = (float*)d_ws;
    float* table = wsf;                            // 3*4128*32 = 1.58 MB
    float* w2t   = wsf + (size_t)3 * PTS * 32;     // 3*512*512 = 3.00 MB
    P.table = table;

    k_prep <<<dim3(16, 16, 3), 256, 0, stream>>>(P, w2t);
    k_siren<<<dim3(NBLK, 3), 256, 0, stream>>>(P, w2t);
    k_ic   <<<NB / 64, 256, 0, stream>>>(table, core, xin, (float*)d_out);
}